// Round 1
// 806.992 us; speedup vs baseline: 1.0065x; 1.0065x over previous
//
#include <hip/hip_runtime.h>
#include <hip/hip_bf16.h>

typedef __bf16 bf16x8 __attribute__((ext_vector_type(8)));
typedef __bf16 bf16x4 __attribute__((ext_vector_type(4)));
typedef __bf16 bf16x2 __attribute__((ext_vector_type(2)));
typedef float  f32x4  __attribute__((ext_vector_type(4)));

#define DIM   1024
#define BSZ   4
#define LSEQ  8192
#define M_TOT (BSZ*LSEQ)      /* 32768 rows */
#define CHUNKS 256
#define CLEN  (LSEQ/CHUNKS)   /* 32 */

__device__ __forceinline__ float sigmoid_f(float z){ return 1.0f/(1.0f + __expf(-z)); }
__device__ __forceinline__ float tanh_f(float z){ return 1.0f - 2.0f/(__expf(2.0f*z) + 1.0f); }

// ---------------- prepass: x (fp32) -> x_hi, x_lo (bf16 split) ----------------
__global__ __launch_bounds__(256) void k_convert_x(const float* __restrict__ x,
                                                   __bf16* __restrict__ xh,
                                                   __bf16* __restrict__ xl){
    int i = (blockIdx.x*256 + threadIdx.x)*4;
    float4 v = *(const float4*)(x + i);
    float vv[4] = {v.x, v.y, v.z, v.w};
    bf16x4 h, l;
#pragma unroll
    for(int j=0;j<4;j++){
        __bf16 hj = (__bf16)vv[j];
        h[j] = hj;
        l[j] = (__bf16)(vv[j] - (float)hj);
    }
    *(bf16x4*)(xh + i) = h;
    *(bf16x4*)(xl + i) = l;
}

// ---------------- prepass: W (fp32, [k][n]) -> WT (bf16, [n][k]), 4 gates ----------------
__global__ __launch_bounds__(256) void k_convert_w(const float* __restrict__ W0,
                                                   const float* __restrict__ W1,
                                                   const float* __restrict__ W2,
                                                   const float* __restrict__ W3,
                                                   __bf16* __restrict__ WT){
    __shared__ float t[32][33];
    int tx = threadIdx.x, ty = threadIdx.y;          // block (32,8)
    int n0 = blockIdx.x*32, k0 = blockIdx.y*32;
    int g = blockIdx.z;
    const float* W = (g==0)?W0:(g==1)?W1:(g==2)?W2:W3;
    __bf16* wt = WT + (size_t)g*DIM*DIM;
#pragma unroll
    for(int j=0;j<4;j++)
        t[ty + j*8][tx] = W[(size_t)(k0 + ty + j*8)*DIM + n0 + tx];
    __syncthreads();
#pragma unroll
    for(int j=0;j<4;j++)
        wt[(size_t)(n0 + ty + j*8)*DIM + k0 + tx] = (__bf16)t[tx][ty + j*8];
}

// ---------------- unified 4-gate GEMM, double-buffered prefetch ----------------
// Block computes 128(M) x 64(N) for ALL 4 gates. A (hi+lo) staged once per K-step.
// LDS: two 32 KiB buffers; per buffer 8 regions x 4 KiB:
//   [0,1]=A_hi rows 0-63/64-127, [2,3]=A_lo, [4..7]=B gate 0..3.
// XOR swizzle: element (row r, k-seg q) lives at r*64 + (q ^ ((r>>1)&3))*16.
// Schedule (T3 minimal 2-phase): STAGE(buf^1, kt+1) issued BEFORE compute(buf, kt);
// ONE __syncthreads per K-step — its vmcnt(0) drain lands after the MFMA phase.
__global__ __launch_bounds__(256,2) void k_gemm(
        const __bf16* __restrict__ xh, const __bf16* __restrict__ xl,
        const __bf16* __restrict__ WT,            // [4][DIM][DIM], n-major
        const float* __restrict__ b0, const float* __restrict__ b1,
        const float* __restrict__ b2, const float* __restrict__ b3,
        __bf16* __restrict__ F, __bf16* __restrict__ INP, __bf16* __restrict__ G)
{
    __shared__ __bf16 smem[2*8*2048];   // 64 KiB (2 buffers x 32 KiB)
    const int tid = threadIdx.x;
    const int nb = blockIdx.x, mb = blockIdx.y;

    const __bf16* ah = xh + (size_t)mb*128*DIM;
    const __bf16* al = xl + (size_t)mb*128*DIM;

    const int lane = tid & 63, wv = tid >> 6;
    const int wm = wv & 1, wn = wv >> 1;          // waves: 2 row-halves x 2 col-halves
    const int quad = lane >> 4, l15 = lane & 15;

    f32x4 acc[4][4][2];
#pragma unroll
    for(int g=0;g<4;g++)
#pragma unroll
        for(int i=0;i<4;i++)
#pragma unroll
            for(int j=0;j<2;j++) acc[g][i][j] = (f32x4){0.f,0.f,0.f,0.f};

    // staging source mapping (undoes the XOR swizzle): thread t -> region row r=t>>2,
    // LDS slot t&3, global seg = (t&3) ^ ((r>>1)&3) = (t&3) ^ ((t>>3)&3)
    const int rA   = tid >> 2;
    const int sseg = ((tid & 3) ^ ((tid >> 3) & 3)) * 8;   // element offset
    char* lds_base = (char*)smem;

    const __bf16* src0 = ah + (size_t)(rA     )*DIM + sseg;
    const __bf16* src1 = ah + (size_t)(64 + rA)*DIM + sseg;
    const __bf16* src2 = al + (size_t)(rA     )*DIM + sseg;
    const __bf16* src3 = al + (size_t)(64 + rA)*DIM + sseg;
    const __bf16* src4 = WT + (size_t)0*DIM*DIM + (size_t)(nb*64 + rA)*DIM + sseg;
    const __bf16* src5 = WT + (size_t)1*DIM*DIM + (size_t)(nb*64 + rA)*DIM + sseg;
    const __bf16* src6 = WT + (size_t)2*DIM*DIM + (size_t)(nb*64 + rA)*DIM + sseg;
    const __bf16* src7 = WT + (size_t)3*DIM*DIM + (size_t)(nb*64 + rA)*DIM + sseg;

#define GLDS(p, dst) __builtin_amdgcn_global_load_lds( \
        (const __attribute__((address_space(1))) void*)(p), \
        (__attribute__((address_space(3))) void*)(dst), 16, 0, 0)

#define STAGE(BUF, K0) do{ \
        char* _db = lds_base + (BUF)*32768; \
        GLDS(src0 + (K0), _db + (0*256+tid)*16); \
        GLDS(src1 + (K0), _db + (1*256+tid)*16); \
        GLDS(src2 + (K0), _db + (2*256+tid)*16); \
        GLDS(src3 + (K0), _db + (3*256+tid)*16); \
        GLDS(src4 + (K0), _db + (4*256+tid)*16); \
        GLDS(src5 + (K0), _db + (5*256+tid)*16); \
        GLDS(src6 + (K0), _db + (6*256+tid)*16); \
        GLDS(src7 + (K0), _db + (7*256+tid)*16); \
    }while(0)

    // fragment read offsets (bytes), swizzle-corrected; constant across i/j since
    // ((base + 16*i)>>1)&3 == (base>>1)&3
    const int rowA  = wm*64 + l15;
    const int offA  = (quad ^ ((rowA>>1)&3))*16;
    const int rowB  = wn*32 + l15;
    const int offB  = (quad ^ ((rowB>>1)&3))*16;

    STAGE(0, 0);
    __syncthreads();                 // vmcnt(0) drain: buffer 0 ready

#pragma unroll 2
    for(int kt=0; kt<DIM/32; ++kt){
        char* cb = lds_base + (kt&1)*32768;        // compute buffer
        if(kt < DIM/32 - 1)
            STAGE((kt+1)&1, (kt+1)*32);            // prefetch next tile (overlaps MFMA)

        bf16x8 fh[4], fl[4];
#pragma unroll
        for(int i=0;i<4;i++){
            int rbyte = (rowA + i*16)*64 + offA;
            fh[i] = *(const bf16x8*)(cb + rbyte);
            fl[i] = *(const bf16x8*)(cb + 8192 + rbyte);
        }
#pragma unroll
        for(int g=0;g<4;g++){
            bf16x8 fb0 = *(const bf16x8*)(cb + 16384 + g*4096 + (rowB     )*64 + offB);
            bf16x8 fb1 = *(const bf16x8*)(cb + 16384 + g*4096 + (rowB + 16)*64 + offB);
#pragma unroll
            for(int i=0;i<4;i++){
                acc[g][i][0] = __builtin_amdgcn_mfma_f32_16x16x32_bf16(fh[i], fb0, acc[g][i][0], 0,0,0);
                acc[g][i][0] = __builtin_amdgcn_mfma_f32_16x16x32_bf16(fl[i], fb0, acc[g][i][0], 0,0,0);
                acc[g][i][1] = __builtin_amdgcn_mfma_f32_16x16x32_bf16(fh[i], fb1, acc[g][i][1], 0,0,0);
                acc[g][i][1] = __builtin_amdgcn_mfma_f32_16x16x32_bf16(fl[i], fb1, acc[g][i][1], 0,0,0);
            }
        }
        __syncthreads();             // drains vmcnt(0) (prefetch done) + lgkmcnt (reads done)
    }
#undef STAGE
#undef GLDS

    // epilogue: f=sig, inp=tanh*sig, og=sig; bf16 stores
#pragma unroll
    for(int j=0;j<2;j++){
        int col = nb*64 + wn*32 + j*16 + l15;
        float bvf = b0[col], bvi = b1[col], bvg = b2[col], bvo = b3[col];
#pragma unroll
        for(int i=0;i<4;i++){
#pragma unroll
            for(int r=0;r<4;r++){
                int m = mb*128 + wm*64 + i*16 + quad*4 + r;
                size_t o = (size_t)m*DIM + col;
                F[o]   = (__bf16)sigmoid_f(acc[0][i][j][r] + bvf);
                float it = tanh_f   (acc[1][i][j][r] + bvi);
                float ig = sigmoid_f(acc[2][i][j][r] + bvg);
                INP[o] = (__bf16)(it*ig);
                G[o]   = (__bf16)sigmoid_f(acc[3][i][j][r] + bvo);
            }
        }
    }
}

// ---------------- scan pass 1: per-chunk (P = prod f, H = local scan from 0) ----------------
// 256 chunks x 4 batches = 1024 blocks; lane owns 4 dims (8 B bf16x4 loads).
__global__ __launch_bounds__(256) void k_scan1(const __bf16* __restrict__ F, const __bf16* __restrict__ INP,
                                               float* __restrict__ P, float* __restrict__ Hc){
    int c = blockIdx.x, b = blockIdx.y;
    int d = threadIdx.x*4;
    size_t base = ((size_t)(b*LSEQ + c*CLEN))*DIM + d;
    float p0=1.f,p1=1.f,p2=1.f,p3=1.f;
    float h0=0.f,h1=0.f,h2=0.f,h3=0.f;
#pragma unroll 4
    for(int t=0;t<CLEN;t++){
        bf16x4 fv = *(const bf16x4*)(F   + base + (size_t)t*DIM);
        bf16x4 iv = *(const bf16x4*)(INP + base + (size_t)t*DIM);
        h0 = (float)fv[0]*h0 + (float)iv[0]; p0 *= (float)fv[0];
        h1 = (float)fv[1]*h1 + (float)iv[1]; p1 *= (float)fv[1];
        h2 = (float)fv[2]*h2 + (float)iv[2]; p2 *= (float)fv[2];
        h3 = (float)fv[3]*h3 + (float)iv[3]; p3 *= (float)fv[3];
    }
    size_t bd = (size_t)c*(BSZ*DIM) + b*DIM + d;
    *(f32x4*)(P  + bd) = (f32x4){p0,p1,p2,p3};
    *(f32x4*)(Hc + bd) = (f32x4){h0,h1,h2,h3};
}

// ---------------- scan pass 2: chunk-level scan, seeded with last_hidden_init ----------------
__global__ __launch_bounds__(256) void k_scan2(const float* __restrict__ P, const float* __restrict__ Hc,
                                               const float* __restrict__ lh, float* __restrict__ Hin){
    int bd = blockIdx.x*256 + threadIdx.x;   // 0..4095
    int d = bd & (DIM-1);
    float h = lh[d];
#pragma unroll 8
    for(int c=0;c<CHUNKS;c++){
        size_t o = (size_t)c*(BSZ*DIM) + bd;
        Hin[o] = h;
        h = P[o]*h + Hc[o];
    }
}

// ---------------- scan pass 3: replay chunks, fuse y = tanh(h)*G ----------------
__global__ __launch_bounds__(256) void k_scan3(const __bf16* __restrict__ F, const __bf16* __restrict__ INP,
                                               const __bf16* __restrict__ G, const float* __restrict__ Hin,
                                               float* __restrict__ Y){
    int c = blockIdx.x, b = blockIdx.y;
    int d = threadIdx.x*4;
    size_t base = ((size_t)(b*LSEQ + c*CLEN))*DIM + d;
    f32x4 hv = *(const f32x4*)(Hin + (size_t)c*(BSZ*DIM) + b*DIM + d);
    float h0=hv[0],h1=hv[1],h2=hv[2],h3=hv[3];
#pragma unroll 4
    for(int t=0;t<CLEN;t++){
        size_t o = base + (size_t)t*DIM;
        bf16x4 fv = *(const bf16x4*)(F + o);
        bf16x4 iv = *(const bf16x4*)(INP + o);
        bf16x4 gv = *(const bf16x4*)(G + o);
        h0 = (float)fv[0]*h0 + (float)iv[0];
        h1 = (float)fv[1]*h1 + (float)iv[1];
        h2 = (float)fv[2]*h2 + (float)iv[2];
        h3 = (float)fv[3]*h3 + (float)iv[3];
        *(f32x4*)(Y + o) = (f32x4){tanh_f(h0)*(float)gv[0], tanh_f(h1)*(float)gv[1],
                                   tanh_f(h2)*(float)gv[2], tanh_f(h3)*(float)gv[3]};
    }
}

extern "C" void kernel_launch(void* const* d_in, const int* in_sizes, int n_in,
                              void* d_out, int out_size, void* d_ws, size_t ws_size,
                              hipStream_t stream){
    const float* x  = (const float*)d_in[0];
    const float* W[4]    = {(const float*)d_in[1], (const float*)d_in[3],
                            (const float*)d_in[5], (const float*)d_in[7]};
    const float* bias[4] = {(const float*)d_in[2], (const float*)d_in[4],
                            (const float*)d_in[6], (const float*)d_in[8]};
    const float* lh = (const float*)d_in[9];
    float* Y = (float*)d_out;

    char* ws = (char*)d_ws;
    __bf16* xh = (__bf16*)(ws);                         //  64 MiB
    __bf16* xl = (__bf16*)(ws + ((size_t) 64<<20));     //  64 MiB
    __bf16* WT = (__bf16*)(ws + ((size_t)128<<20));     //   8 MiB
    __bf16* F  = (__bf16*)(ws + ((size_t)136<<20));     //  64 MiB
    __bf16* INP= (__bf16*)(ws + ((size_t)200<<20));     //  64 MiB
    __bf16* G  = (__bf16*)(ws + ((size_t)264<<20));     //  64 MiB
    // P/Hc/Hin (4 MiB each with CHUNKS=256) alias the xh region: xh/xl are dead
    // after k_gemm, and all dispatches are stream-ordered (safe under graph
    // capture and per-pass rocprof replay, which re-runs the full sequence).
    float*  P  = (float*) (ws);                         //   4 MiB (over xh)
    float*  Hc = (float*) (ws + ((size_t)  4<<20));     //   4 MiB
    float*  Hin= (float*) (ws + ((size_t)  8<<20));     //   4 MiB  (total still 328 MiB)

    hipLaunchKernelGGL(k_convert_x, dim3(M_TOT*DIM/(4*256)), dim3(256), 0, stream, x, xh, xl);
    hipLaunchKernelGGL(k_convert_w, dim3(32,32,4), dim3(32,8), 0, stream,
                       W[0], W[1], W[2], W[3], WT);
    hipLaunchKernelGGL(k_gemm, dim3(16, M_TOT/128), dim3(256), 0, stream,
                       xh, xl, WT, bias[0], bias[1], bias[2], bias[3], F, INP, G);
    hipLaunchKernelGGL(k_scan1, dim3(CHUNKS, BSZ), dim3(256), 0, stream, F, INP, P, Hc);
    hipLaunchKernelGGL(k_scan2, dim3(BSZ*DIM/256), dim3(256), 0, stream, P, Hc, lh, Hin);
    hipLaunchKernelGGL(k_scan3, dim3(CHUNKS, BSZ), dim3(256), 0, stream, F, INP, G, Hin, Y);
}